// Round 2
// baseline (586.127 us; speedup 1.0000x reference)
//
#include <hip/hip_runtime.h>

// Spiking NN collapses to 3 dependent masked binary matvecs (input drive is
// nonzero only at t=0; decaying membranes can never re-cross threshold):
//   enc = (u < x);  s0 = (W0*M0)@enc > 1;  s1 = (W1*M1)@s0 > 1;
//   out = ((W2*M2)@s1 > 1) ? 1/time_steps : 0
// HBM-bound: 384 MB streamed once (floor ~57 us at the 6.75 TB/s the harness
// fills achieve). v3: single PLAIN kernel (cooperative launch was silently
// rejected by the harness in v2 -> all-zero output). Manual grid barrier:
// 1024 blocks @ launch_bounds(256,4) = exactly 4 blocks/CU x 256 CU, whole
// grid co-resident by construction, so an atomic counter barrier cannot
// deadlock. Device-scope fences handle cross-XCD L2 non-coherence.

constexpr int N = 4096;
constexpr int NBLOCKS = N / 4;   // 1024 = full-machine residency at 4 blk/CU
typedef float f32x4 __attribute__((ext_vector_type(4)));

__device__ __forceinline__ void grid_barrier(int* cnt)
{
    __syncthreads();                       // drains this block's stores (vmcnt 0)
    if (threadIdx.x == 0) {
        __threadfence();                   // release: L2 writeback (agent scope)
        atomicAdd(cnt, 1);                 // device-scope RMW at coherence point
        while (__hip_atomic_load(cnt, __ATOMIC_RELAXED,
                                 __HIP_MEMORY_SCOPE_AGENT) < NBLOCKS)
            __builtin_amdgcn_s_sleep(8);
        __threadfence();                   // acquire: invalidate stale L1/L2
    }
    __syncthreads();
}

template <bool ENCODE, bool FINAL>
__device__ __forceinline__ void snn_phase(
    const float* __restrict__ W, const float* __restrict__ Mk,
    const float* __restrict__ S, const float* __restrict__ U,
    const int* __restrict__ t_steps, float* __restrict__ out,
    const int row, const int lane)
{
    const f32x4* W4 = reinterpret_cast<const f32x4*>(W + (size_t)row * N);
    const f32x4* M4 = reinterpret_cast<const f32x4*>(Mk + (size_t)row * N);
    const f32x4* S4 = reinterpret_cast<const f32x4*>(S);
    const f32x4* U4 = reinterpret_cast<const f32x4*>(U);

    // 4 independent chains: 16-deep each instead of one 64-deep chain.
    double a0 = 0.0, a1 = 0.0, a2 = 0.0, a3 = 0.0;
#pragma unroll
    for (int it = 0; it < N / 4 / 64; ++it) {           // 16 iterations
        const int idx = it * 64 + lane;                 // coalesced: 1 KB/wave
        f32x4 w = __builtin_nontemporal_load(&W4[idx]); // single-use stream
        f32x4 m = __builtin_nontemporal_load(&M4[idx]); // single-use stream
        f32x4 s = S4[idx];                              // broadcast, cacheable
        if (ENCODE) {
            f32x4 uu = U4[idx];
            s.x = (uu.x < s.x) ? 1.0f : 0.0f;
            s.y = (uu.y < s.y) ? 1.0f : 0.0f;
            s.z = (uu.z < s.z) ? 1.0f : 0.0f;
            s.w = (uu.w < s.w) ? 1.0f : 0.0f;
        }
        // m and s are exact {0,1}; w*(m*s) is exact in f64 -> near-exact sum
        a0 = fma((double)w.x, (double)(m.x * s.x), a0);
        a1 = fma((double)w.y, (double)(m.y * s.y), a1);
        a2 = fma((double)w.z, (double)(m.z * s.z), a2);
        a3 = fma((double)w.w, (double)(m.w * s.w), a3);
    }
    double acc = (a0 + a1) + (a2 + a3);
#pragma unroll
    for (int off = 32; off > 0; off >>= 1)
        acc += __shfl_down(acc, off, 64);

    if (lane == 0) {
        if (FINAL) {
            out[row] = (acc > 1.0) ? (1.0f / (float)t_steps[0]) : 0.0f;
        } else {
            out[row] = (acc > 1.0) ? 1.0f : 0.0f;
        }
    }
}

__global__ __launch_bounds__(256, 4) void snn_fused(
    const float* __restrict__ x,  const float* __restrict__ u,
    const float* __restrict__ W0, const float* __restrict__ W1,
    const float* __restrict__ W2, const float* __restrict__ M0,
    const float* __restrict__ M1, const float* __restrict__ M2,
    const int* __restrict__ t_steps, float* __restrict__ out,
    float* __restrict__ s0, float* __restrict__ s1, int* bar)
{
    const int lane = threadIdx.x & 63;
    const int wave = threadIdx.x >> 6;
    const int row  = (blockIdx.x << 2) | wave;          // 1 wave per row

    snn_phase<true,  false>(W0, M0, x,  u,       nullptr, s0, row, lane);
    grid_barrier(bar + 0);
    snn_phase<false, false>(W1, M1, s0, nullptr, nullptr, s1, row, lane);
    grid_barrier(bar + 16);                              // separate cacheline-ish
    snn_phase<false, true >(W2, M2, s1, nullptr, t_steps, out, row, lane);
}

extern "C" void kernel_launch(void* const* d_in, const int* in_sizes, int n_in,
                              void* d_out, int out_size, void* d_ws, size_t ws_size,
                              hipStream_t stream)
{
    const float* x  = (const float*)d_in[0];
    const float* u  = (const float*)d_in[1];
    const float* W0 = (const float*)d_in[2];
    const float* W1 = (const float*)d_in[3];
    const float* W2 = (const float*)d_in[4];
    const float* M0 = (const float*)d_in[5];
    const float* M1 = (const float*)d_in[6];
    const float* M2 = (const float*)d_in[7];
    const int* t_steps = (const int*)d_in[8];
    float* out = (float*)d_out;

    float* s0 = (float*)d_ws;           // 4096 floats, fully rewritten each call
    float* s1 = s0 + N;                 // 4096 floats
    int*  bar = (int*)(s1 + N);         // 2 barrier counters (+padding)

    // Workspace is re-poisoned between iterations: re-zero barrier counters
    // every call (capture-legal stream op).
    hipMemsetAsync(bar, 0, 32 * sizeof(int), stream);

    snn_fused<<<dim3(NBLOCKS), dim3(256), 0, stream>>>(
        x, u, W0, W1, W2, M0, M1, M2, t_steps, out, s0, s1, bar);
}